// Round 6
// baseline (47.978 us; speedup 1.0000x reference)
//
#include <hip/hip_runtime.h>
#include <math.h>

// Problem constants (from reference)
#define NN      131072          // ROWS*COLS*P = 64*64*32
#define Q       10
#define T1      8
#define GRID    2048
#define BLOCK   256
#define SWEEP   (GRID * BLOCK)  // 524288 float2s per grid sweep; E_F2 = 20 * SWEEP exactly

// d_out layout (float32, concatenated in return order):
//   [0, 10)                         prediction
//   [10, 10 + N*Q*T1)               voter_in[0]   (10,485,760)
//   [10 + N*Q*T1, ... + 2*N*Q*T1)   votes         (20,971,520)
#define VIN0_OFF   10u
#define VIN0_SZ    (NN * Q * T1)            // 10485760
#define VOTES_OFF  (VIN0_OFF + VIN0_SZ)     // 10485770 (8B-aligned)
#define VOTES_SZ   (2u * NN * Q * T1)       // 20971520
#define E_F2       (VOTES_SZ / 2u)          // 10,485,760 float2s of votes

// One j-step: j -> row r = j>>2 (s,i,q), slot = j&3 covering bins {2*slot, 2*slot+1}.
// Branchless: unconditional clamped-index weight load (pipelineable), float-equality
// one-hot (Inf/NaN -> all-zero, matching reference). EMIT_VIN is compile-time (s==0).
template <bool EMIT_VIN>
__device__ __forceinline__ void dtnn_step(
    unsigned int j,
    const float* __restrict__ spikes,
    const float* __restrict__ weights,
    float2* __restrict__ votes2,
    float2* __restrict__ vin2,
    unsigned int lane,
    unsigned int& acc)
{
    const unsigned int r    = j >> 2;
    const unsigned int slot = j & 3u;
    const unsigned int ri   = r / Q;
    const unsigned int q    = r - Q * ri;
    const unsigned int i    = ri & (NN - 1u);

    float v = spikes[i];
    v = (v >= 7.0f && !isinf(v)) ? 7.0f : v;      // clamp finite >= tau_eff; Inf passes
    const float t0 = (float)(2u * slot);
    const bool  h0 = (v == t0);
    const bool  h1 = (v == t0 + 1.0f);

    int tv = (int)v;                               // Inf->INT_MAX, NaN->0 (HW saturating cvt)
    tv = tv < 0 ? 0 : (tv > 7 ? 7 : tv);
    const float w  = weights[r * 8u + (unsigned)tv];   // unconditional: no divergence, MLP-friendly
    const bool  gw = (w >= 3.5f);

    const float vx = (h0 && gw) ? 1.0f : 0.0f;
    const float vy = (h1 && gw) ? 1.0f : 0.0f;
    votes2[j] = make_float2(vx, vy);

    if (EMIT_VIN)                                   // independent of weight load
        vin2[j] = make_float2(h0 ? 1.0f : 0.0f, h1 ? 1.0f : 0.0f);

    const bool inc = (h0 && gw) || (h1 && gw);
    #pragma unroll
    for (int k = 0; k < Q; ++k) {
        const unsigned long long m = __ballot(inc && (q == (unsigned)k));
        if (lane == (unsigned)k) acc += (unsigned)__popcll(m);
    }
}

__global__ __launch_bounds__(BLOCK) void dtnn_main(
    const float* __restrict__ spikes,   // (N,)
    const float* __restrict__ weights,  // (2, N, Q, T1)
    float* __restrict__ out,
    unsigned int* __restrict__ tallies) // (Q, GRID)
{
    const unsigned int lane = threadIdx.x & 63u;
    const unsigned int wid  = threadIdx.x >> 6;   // 4 waves/block

    float2* __restrict__ votes2 = (float2*)(out + VOTES_OFF);
    float2* __restrict__ vin2   = (float2*)(out + VIN0_OFF);

    unsigned int acc = 0u;   // lane k (<10) accumulates tally for class k
    unsigned int j   = blockIdx.x * BLOCK + threadIdx.x;

    // it in [0,10): r < NN*Q  <=> s == 0 -> also emit voter_in[0]
    #pragma unroll 5
    for (int it = 0; it < 10; ++it) {
        dtnn_step<true>(j, spikes, weights, votes2, vin2, lane, acc);
        j += SWEEP;
    }
    // it in [10,20): s == 1 -> votes only
    #pragma unroll 5
    for (int it = 10; it < 20; ++it) {
        dtnn_step<false>(j, spikes, weights, votes2, vin2, lane, acc);
        j += SWEEP;
    }

    // Combine 4 waves' lane-resident tallies via plain LDS stores.
    __shared__ unsigned int lt[4 * Q];
    if (lane < Q) lt[wid * Q + lane] = acc;
    __syncthreads();
    if (threadIdx.x < Q) {
        tallies[threadIdx.x * GRID + blockIdx.x] =
            lt[threadIdx.x] + lt[Q + threadIdx.x] + lt[2 * Q + threadIdx.x] + lt[3 * Q + threadIdx.x];
    }
}

// One wave per class: coalesced partial loads + shuffle reduction.
__global__ __launch_bounds__(64 * Q) void dtnn_pred(
    const unsigned int* __restrict__ tallies,  // (Q, GRID)
    float* __restrict__ out)
{
    const unsigned int lane = threadIdx.x & 63u;
    const unsigned int q    = threadIdx.x >> 6;    // 0..9

    unsigned int s = 0;
    #pragma unroll
    for (int it = 0; it < GRID / 64; ++it)
        s += tallies[q * GRID + it * 64 + lane];
    #pragma unroll
    for (int off = 32; off >= 1; off >>= 1)
        s += __shfl_down(s, off, 64);

    __shared__ unsigned int sums[Q];
    if (lane == 0) sums[q] = s;
    __syncthreads();

    if (threadIdx.x == 0) {
        unsigned int best = sums[0]; int bi = 0;
        #pragma unroll
        for (int k = 1; k < Q; ++k)
            if (sums[k] > best) { best = sums[k]; bi = k; }   // first-index tie-break
        #pragma unroll
        for (int k = 0; k < Q; ++k) out[k] = (k == bi) ? 1.0f : 0.0f;
    }
}

extern "C" void kernel_launch(void* const* d_in, const int* in_sizes, int n_in,
                              void* d_out, int out_size, void* d_ws, size_t ws_size,
                              hipStream_t stream) {
    const float* spikes  = (const float*)d_in[0];   // (64,64,32) float32
    const float* weights = (const float*)d_in[1];   // (2, N, Q, T1) float32
    float* out = (float*)d_out;
    unsigned int* tallies = (unsigned int*)d_ws;    // Q * GRID uints = 80 KB

    dtnn_main<<<GRID, BLOCK, 0, stream>>>(spikes, weights, out, tallies);
    dtnn_pred<<<1, 64 * Q, 0, stream>>>(tallies, out);
}

// Round 7
// 43.874 us; speedup vs baseline: 1.0935x; 1.0935x over previous
//
#include <hip/hip_runtime.h>
#include <math.h>

// Problem constants (from reference)
#define NN      131072          // ROWS*COLS*P = 64*64*32
#define Q       10
#define T1      8
#define GRID    2048
#define BLOCK   256

// d_out layout (float32, concatenated in return order):
//   [0, 10)                         prediction
//   [10, 10 + N*Q*T1)               voter_in[0]   (10,485,760)
//   [10 + N*Q*T1, ... + 2*N*Q*T1)   votes         (20,971,520)
#define VIN0_OFF   10u
#define VIN0_SZ    (NN * Q * T1)            // 10485760
#define VOTES_OFF  (VIN0_OFF + VIN0_SZ)     // 10485770 (8B-aligned)
#define VOTES_SZ   (2u * NN * Q * T1)       // 20971520
#define E_F2       (VOTES_SZ / 2u)          // 10,485,760 float2s of votes

// R3 structure; ONE isolated change: the weight load is unconditional with a
// clamped in-row index (no exec-mask divergence around the load), so the
// scheduler can keep multiple iterations' loads in flight. Semantics preserved:
// votes still gate on exact bin equality (h0/h1), and when h0|h1 holds the
// clamped tv equals the matching bin, so the loaded weight is the right one.
__global__ __launch_bounds__(BLOCK) void dtnn_main(
    const float* __restrict__ spikes,   // (N,)
    const float* __restrict__ weights,  // (2, N, Q, T1)
    float* __restrict__ out,
    unsigned int* __restrict__ tallies) // (Q, GRID)
{
    const unsigned int lane = threadIdx.x & 63u;
    const unsigned int wid  = threadIdx.x >> 6;   // 4 waves/block

    float2* __restrict__ votes2 = (float2*)(out + VOTES_OFF);
    float2* __restrict__ vin2   = (float2*)(out + VIN0_OFF);

    unsigned int acc = 0u;   // lane k (<10) accumulates tally for class k

    const unsigned int stride = GRID * BLOCK;
    for (unsigned int j = blockIdx.x * BLOCK + threadIdx.x; j < E_F2; j += stride) {
        const unsigned int r    = j >> 2;          // (s,i,q) row
        const unsigned int slot = j & 3u;          // which float2 of the 8-bin row
        const unsigned int ri   = r / Q;           // s*N + i
        const unsigned int q    = r - Q * ri;      // r % 10
        const unsigned int i    = ri & (NN - 1u);

        float v = spikes[i];
        v = (v >= 7.0f && !isinf(v)) ? 7.0f : v;   // clamp finite >= tau_eff; Inf passes
        const float t0 = (float)(2u * slot);
        const bool  h0 = (v == t0);                // exact one-hot (Inf/NaN -> all zero)
        const bool  h1 = (v == t0 + 1.0f);

        int tv = (int)v;                           // {0..7} for this input; saturates on Inf
        tv = tv < 0 ? 0 : (tv > 7 ? 7 : tv);       // defensive in-row clamp
        const float w  = weights[r * 8u + (unsigned)tv];   // UNCONDITIONAL: pipelineable
        const bool  gw = (w >= 3.5f);

        const float vx = (h0 && gw) ? 1.0f : 0.0f;
        const float vy = (h1 && gw) ? 1.0f : 0.0f;
        votes2[j] = make_float2(vx, vy);

        if (r < NN * Q) {                          // s == 0: emit voter_in[0]
            vin2[j] = make_float2(h0 ? 1.0f : 0.0f, h1 ? 1.0f : 0.0f);
        }

        // Wave-level tally: 10 ballots, zero LDS traffic (R3-proven).
        const bool inc = (vx != 0.0f) | (vy != 0.0f);
        #pragma unroll
        for (int k = 0; k < Q; ++k) {
            const unsigned long long m = __ballot(inc && (q == (unsigned)k));
            if (lane == (unsigned)k) acc += (unsigned)__popcll(m);
        }
    }

    // Combine 4 waves' lane-resident tallies via plain LDS stores.
    __shared__ unsigned int lt[4 * Q];
    if (lane < Q) lt[wid * Q + lane] = acc;
    __syncthreads();
    if (threadIdx.x < Q) {
        tallies[threadIdx.x * GRID + blockIdx.x] =
            lt[threadIdx.x] + lt[Q + threadIdx.x] + lt[2 * Q + threadIdx.x] + lt[3 * Q + threadIdx.x];
    }
}

// One wave per class: coalesced partial loads + shuffle reduction.
__global__ __launch_bounds__(64 * Q) void dtnn_pred(
    const unsigned int* __restrict__ tallies,  // (Q, GRID)
    float* __restrict__ out)
{
    const unsigned int lane = threadIdx.x & 63u;
    const unsigned int q    = threadIdx.x >> 6;    // 0..9

    unsigned int s = 0;
    #pragma unroll
    for (int it = 0; it < GRID / 64; ++it)
        s += tallies[q * GRID + it * 64 + lane];
    #pragma unroll
    for (int off = 32; off >= 1; off >>= 1)
        s += __shfl_down(s, off, 64);

    __shared__ unsigned int sums[Q];
    if (lane == 0) sums[q] = s;
    __syncthreads();

    if (threadIdx.x == 0) {
        unsigned int best = sums[0]; int bi = 0;
        #pragma unroll
        for (int k = 1; k < Q; ++k)
            if (sums[k] > best) { best = sums[k]; bi = k; }   // first-index tie-break
        #pragma unroll
        for (int k = 0; k < Q; ++k) out[k] = (k == bi) ? 1.0f : 0.0f;
    }
}

extern "C" void kernel_launch(void* const* d_in, const int* in_sizes, int n_in,
                              void* d_out, int out_size, void* d_ws, size_t ws_size,
                              hipStream_t stream) {
    const float* spikes  = (const float*)d_in[0];   // (64,64,32) float32
    const float* weights = (const float*)d_in[1];   // (2, N, Q, T1) float32
    float* out = (float*)d_out;
    unsigned int* tallies = (unsigned int*)d_ws;    // Q * GRID uints = 80 KB

    dtnn_main<<<GRID, BLOCK, 0, stream>>>(spikes, weights, out, tallies);
    dtnn_pred<<<1, 64 * Q, 0, stream>>>(tallies, out);
}

// Round 8
// 40.936 us; speedup vs baseline: 1.1720x; 1.0718x over previous
//
#include <hip/hip_runtime.h>
#include <math.h>

// Problem constants (from reference)
#define NN      131072          // ROWS*COLS*P = 64*64*32
#define Q       10
#define T1      8
#define GRID    2048
#define BLOCK   256
#define CHUNK   (E_F2 / GRID)   // 5120 float2s per block = 20 iters * 256 threads exactly

// d_out layout (float32, concatenated in return order):
//   [0, 10)                         prediction
//   [10, 10 + N*Q*T1)               voter_in[0]   (10,485,760)
//   [10 + N*Q*T1, ... + 2*N*Q*T1)   votes         (20,971,520)
#define VIN0_OFF   10u
#define VIN0_SZ    (NN * Q * T1)            // 10485760
#define VOTES_OFF  (VIN0_OFF + VIN0_SZ)     // 10485770 (8B-aligned)
#define VOTES_SZ   (2u * NN * Q * T1)       // 20971520
#define E_F2       (VOTES_SZ / 2u)          // 10,485,760 float2s of votes

// R3 body verbatim; ONE isolated change: CONTIGUOUS per-block chunking instead
// of grid-stride sweeps. Each block walks a sequential 40 KB range of each
// output stream (256 threads x 8B x 20 iters), so every block's HBM streams
// are strictly sequential -> maximal row-buffer locality, no 4 MB jumps.
__global__ __launch_bounds__(BLOCK) void dtnn_main(
    const float* __restrict__ spikes,   // (N,)
    const float* __restrict__ weights,  // (2, N, Q, T1)
    float* __restrict__ out,
    unsigned int* __restrict__ tallies) // (Q, GRID)
{
    const unsigned int lane = threadIdx.x & 63u;
    const unsigned int wid  = threadIdx.x >> 6;   // 4 waves/block

    float2* __restrict__ votes2 = (float2*)(out + VOTES_OFF);
    float2* __restrict__ vin2   = (float2*)(out + VIN0_OFF);

    unsigned int acc = 0u;   // lane k (<10) accumulates tally for class k

    const unsigned int jbase = blockIdx.x * (unsigned int)CHUNK + threadIdx.x;
    #pragma unroll 1
    for (unsigned int it = 0; it < CHUNK / BLOCK; ++it) {
        const unsigned int j    = jbase + it * BLOCK;
        const unsigned int r    = j >> 2;          // (s,i,q) row
        const unsigned int slot = j & 3u;          // which float2 of the 8-bin row
        const unsigned int ri   = r / Q;           // s*N + i
        const unsigned int q    = r - Q * ri;      // r % 10
        const unsigned int i    = ri & (NN - 1u);

        float v = spikes[i];
        if (v >= 7.0f && !isinf(v)) v = 7.0f;      // clamp finite >= tau_eff
        const int  tv    = (int)v;
        const bool valid = (v >= 0.0f) && (v < 8.0f) && ((float)tv == v);
        const bool owns  = valid && ((unsigned)(tv >> 1) == slot);

        float2 o   = make_float2(0.0f, 0.0f);
        bool   inc = false;
        if (owns) {                                 // exec-masked scalar load (R3-proven)
            const float w    = weights[r * 8u + (unsigned)tv];
            const float vote = (w >= 3.5f) ? 1.0f : 0.0f;
            if (tv & 1) o.y = vote; else o.x = vote;
            inc = (vote != 0.0f);
        }
        votes2[j] = o;

        if (r < NN * Q) {                           // s == 0 (block-uniform branch here)
            float2 h = make_float2(0.0f, 0.0f);
            if (owns) { if (tv & 1) h.y = 1.0f; else h.x = 1.0f; }
            vin2[j] = h;
        }

        // Wave-level tally: 10 ballots, zero LDS traffic (R3-proven).
        #pragma unroll
        for (int k = 0; k < Q; ++k) {
            const unsigned long long m = __ballot(inc && (q == (unsigned)k));
            if (lane == (unsigned)k) acc += (unsigned)__popcll(m);
        }
    }

    // Combine 4 waves' lane-resident tallies via plain LDS stores.
    __shared__ unsigned int lt[4 * Q];
    if (lane < Q) lt[wid * Q + lane] = acc;
    __syncthreads();
    if (threadIdx.x < Q) {
        tallies[threadIdx.x * GRID + blockIdx.x] =
            lt[threadIdx.x] + lt[Q + threadIdx.x] + lt[2 * Q + threadIdx.x] + lt[3 * Q + threadIdx.x];
    }
}

// One wave per class: coalesced partial loads + shuffle reduction.
__global__ __launch_bounds__(64 * Q) void dtnn_pred(
    const unsigned int* __restrict__ tallies,  // (Q, GRID)
    float* __restrict__ out)
{
    const unsigned int lane = threadIdx.x & 63u;
    const unsigned int q    = threadIdx.x >> 6;    // 0..9

    unsigned int s = 0;
    #pragma unroll
    for (int it = 0; it < GRID / 64; ++it)
        s += tallies[q * GRID + it * 64 + lane];
    #pragma unroll
    for (int off = 32; off >= 1; off >>= 1)
        s += __shfl_down(s, off, 64);

    __shared__ unsigned int sums[Q];
    if (lane == 0) sums[q] = s;
    __syncthreads();

    if (threadIdx.x == 0) {
        unsigned int best = sums[0]; int bi = 0;
        #pragma unroll
        for (int k = 1; k < Q; ++k)
            if (sums[k] > best) { best = sums[k]; bi = k; }   // first-index tie-break
        #pragma unroll
        for (int k = 0; k < Q; ++k) out[k] = (k == bi) ? 1.0f : 0.0f;
    }
}

extern "C" void kernel_launch(void* const* d_in, const int* in_sizes, int n_in,
                              void* d_out, int out_size, void* d_ws, size_t ws_size,
                              hipStream_t stream) {
    const float* spikes  = (const float*)d_in[0];   // (64,64,32) float32
    const float* weights = (const float*)d_in[1];   // (2, N, Q, T1) float32
    float* out = (float*)d_out;
    unsigned int* tallies = (unsigned int*)d_ws;    // Q * GRID uints = 80 KB

    dtnn_main<<<GRID, BLOCK, 0, stream>>>(spikes, weights, out, tallies);
    dtnn_pred<<<1, 64 * Q, 0, stream>>>(tallies, out);
}